// Round 1
// baseline (1814.158 us; speedup 1.0000x reference)
//
#include <hip/hip_runtime.h>

#define N_NODES 100000
#define N_EDGES 1000000
#define IN_DIM 32
#define HID_DIM 64

// ---------------- scatter (sum + count) kernels ----------------

__global__ __launch_bounds__(256) void k_scatter1(
    const float* __restrict__ x,     // [N][32]
    const int* __restrict__ ei,      // [2][E]
    const int* __restrict__ ea,      // [E][2]
    float* __restrict__ agg,         // [2][N][32]
    float* __restrict__ cnt)         // [2][N]
{
    int t = blockIdx.x * 256 + threadIdx.x;
    int e = t >> 5;
    int f = t & 31;
    if (e >= N_EDGES) return;
    int src = ei[e];
    int dst = ei[N_EDGES + e];
    int rel = ea[2 * e + 1];
    float v = x[(size_t)src * IN_DIM + f];
    atomicAdd(&agg[((size_t)rel * N_NODES + (size_t)dst) * IN_DIM + f], v);
    if (f == 0) atomicAdd(&cnt[(size_t)rel * N_NODES + dst], 1.0f);
}

__global__ __launch_bounds__(256) void k_scatter2(
    const float* __restrict__ h1,    // [N][64]
    const int* __restrict__ ei,
    const int* __restrict__ ea,
    float* __restrict__ agg)         // [2][N][64]
{
    int t = blockIdx.x * 256 + threadIdx.x;
    int e = t >> 6;
    int f = t & 63;
    if (e >= N_EDGES) return;
    int src = ei[e];
    int dst = ei[N_EDGES + e];
    int rel = ea[2 * e + 1];
    float v = h1[(size_t)src * HID_DIM + f];
    atomicAdd(&agg[((size_t)rel * N_NODES + (size_t)dst) * HID_DIM + f], v);
}

// ---------------- node-update kernels ----------------
// 256 threads = 4 waves. Each wave: 64 lanes = one output feature j each,
// register-blocked over 4 nodes so one LDS weight read feeds 4 FMAs per matrix.

#define NODES_PER_BLOCK 64   // 4 waves * 4 nodes * 4 iters

__global__ __launch_bounds__(256) void k_layer1(
    const float* __restrict__ x,      // [N][32]
    const float* __restrict__ agg,    // [2][N][32]
    const float* __restrict__ cnt,    // [2][N]
    const float* __restrict__ root1,  // [32][64]
    const float* __restrict__ W1,     // [2][32][64]
    const float* __restrict__ b1,     // [64]
    float* __restrict__ h1)           // [N][64]
{
    __shared__ float wR[IN_DIM * HID_DIM];
    __shared__ float w0[IN_DIM * HID_DIM];
    __shared__ float w1s[IN_DIM * HID_DIM];
    int tid = threadIdx.x;
    for (int i = tid; i < IN_DIM * HID_DIM; i += 256) {
        wR[i]  = root1[i];
        w0[i]  = W1[i];
        w1s[i] = W1[IN_DIM * HID_DIM + i];
    }
    __syncthreads();

    int j   = tid & 63;   // output feature
    int sub = tid >> 6;   // wave id 0..3
    float bj = b1[j];
    int base = blockIdx.x * NODES_PER_BLOCK;

    for (int it = 0; it < 4; ++it) {
        int n0 = base + it * 16 + sub * 4;   // group of 4 nodes (N%4==0 so full)
        if (n0 >= N_NODES) continue;

        float accR[4] = {0, 0, 0, 0};
        float acc0[4] = {0, 0, 0, 0};
        float acc1[4] = {0, 0, 0, 0};

#pragma unroll
        for (int kk = 0; kk < IN_DIM / 4; ++kk) {
            float4 xa[4], q0[4], q1[4];
#pragma unroll
            for (int i = 0; i < 4; ++i) {
                size_t n = (size_t)(n0 + i);
                xa[i] = *(const float4*)(x   + n * IN_DIM + kk * 4);
                q0[i] = *(const float4*)(agg + n * IN_DIM + kk * 4);
                q1[i] = *(const float4*)(agg + ((size_t)N_NODES + n) * IN_DIM + kk * 4);
            }
#pragma unroll
            for (int c = 0; c < 4; ++c) {
                int k = kk * 4 + c;
                float wRk = wR[k * 64 + j];
                float w0k = w0[k * 64 + j];
                float w1k = w1s[k * 64 + j];
#pragma unroll
                for (int i = 0; i < 4; ++i) {
                    float xk  = ((const float*)&xa[i])[c];
                    float a0k = ((const float*)&q0[i])[c];
                    float a1k = ((const float*)&q1[i])[c];
                    accR[i] = fmaf(xk,  wRk, accR[i]);
                    acc0[i] = fmaf(a0k, w0k, acc0[i]);
                    acc1[i] = fmaf(a1k, w1k, acc1[i]);
                }
            }
        }

#pragma unroll
        for (int i = 0; i < 4; ++i) {
            int n = n0 + i;
            float ic0 = 1.0f / fmaxf(cnt[n], 1.0f);
            float ic1 = 1.0f / fmaxf(cnt[N_NODES + n], 1.0f);
            float o = accR[i] + bj + acc0[i] * ic0 + acc1[i] * ic1;
            h1[(size_t)n * HID_DIM + j] = fmaxf(o, 0.0f);
        }
    }
}

__global__ __launch_bounds__(256) void k_layer2_cls(
    const float* __restrict__ h1,     // [N][64]
    const float* __restrict__ agg,    // [2][N][64]
    const float* __restrict__ cnt,    // [2][N]
    const float* __restrict__ root2,  // [64][64]
    const float* __restrict__ W2,     // [2][64][64]
    const float* __restrict__ b2,     // [64]
    const float* __restrict__ Wc,     // [64][2]
    const float* __restrict__ bc,     // [2]
    float* __restrict__ out)          // [N][2]
{
    __shared__ float wR[HID_DIM * HID_DIM];
    __shared__ float w0[HID_DIM * HID_DIM];
    __shared__ float w1s[HID_DIM * HID_DIM];
    __shared__ float wc[HID_DIM * 2];
    int tid = threadIdx.x;
    for (int i = tid; i < HID_DIM * HID_DIM; i += 256) {
        wR[i]  = root2[i];
        w0[i]  = W2[i];
        w1s[i] = W2[HID_DIM * HID_DIM + i];
    }
    if (tid < HID_DIM * 2) wc[tid] = Wc[tid];
    __syncthreads();

    int j   = tid & 63;
    int sub = tid >> 6;
    float bj  = b2[j];
    float bc0 = bc[0], bc1 = bc[1];
    int base = blockIdx.x * NODES_PER_BLOCK;

    for (int it = 0; it < 4; ++it) {
        int n0 = base + it * 16 + sub * 4;
        if (n0 >= N_NODES) continue;

        float accR[4] = {0, 0, 0, 0};
        float acc0[4] = {0, 0, 0, 0};
        float acc1[4] = {0, 0, 0, 0};

#pragma unroll
        for (int kk = 0; kk < HID_DIM / 4; ++kk) {
            float4 xa[4], q0[4], q1[4];
#pragma unroll
            for (int i = 0; i < 4; ++i) {
                size_t n = (size_t)(n0 + i);
                xa[i] = *(const float4*)(h1  + n * HID_DIM + kk * 4);
                q0[i] = *(const float4*)(agg + n * HID_DIM + kk * 4);
                q1[i] = *(const float4*)(agg + ((size_t)N_NODES + n) * HID_DIM + kk * 4);
            }
#pragma unroll
            for (int c = 0; c < 4; ++c) {
                int k = kk * 4 + c;
                float wRk = wR[k * 64 + j];
                float w0k = w0[k * 64 + j];
                float w1k = w1s[k * 64 + j];
#pragma unroll
                for (int i = 0; i < 4; ++i) {
                    float xk  = ((const float*)&xa[i])[c];
                    float a0k = ((const float*)&q0[i])[c];
                    float a1k = ((const float*)&q1[i])[c];
                    accR[i] = fmaf(xk,  wRk, accR[i]);
                    acc0[i] = fmaf(a0k, w0k, acc0[i]);
                    acc1[i] = fmaf(a1k, w1k, acc1[i]);
                }
            }
        }

#pragma unroll
        for (int i = 0; i < 4; ++i) {
            int n = n0 + i;
            float ic0 = 1.0f / fmaxf(cnt[n], 1.0f);
            float ic1 = 1.0f / fmaxf(cnt[N_NODES + n], 1.0f);
            float h2 = fmaxf(accR[i] + bj + acc0[i] * ic0 + acc1[i] * ic1, 0.0f);
            float v0 = h2 * wc[2 * j];
            float v1 = h2 * wc[2 * j + 1];
#pragma unroll
            for (int off = 32; off >= 1; off >>= 1) {
                v0 += __shfl_xor(v0, off);
                v1 += __shfl_xor(v1, off);
            }
            if (j == 0) {
                out[(size_t)n * 2 + 0] = v0 + bc0;
                out[(size_t)n * 2 + 1] = v1 + bc1;
            }
        }
    }
}

// ---------------- launch ----------------

extern "C" void kernel_launch(void* const* d_in, const int* in_sizes, int n_in,
                              void* d_out, int out_size, void* d_ws, size_t ws_size,
                              hipStream_t stream) {
    const float* x     = (const float*)d_in[0];
    const int*   ei    = (const int*)d_in[1];
    const int*   ea    = (const int*)d_in[2];
    const float* W1    = (const float*)d_in[3];
    const float* root1 = (const float*)d_in[4];
    const float* b1    = (const float*)d_in[5];
    const float* W2    = (const float*)d_in[6];
    const float* root2 = (const float*)d_in[7];
    const float* b2    = (const float*)d_in[8];
    const float* Wc    = (const float*)d_in[9];
    const float* bc    = (const float*)d_in[10];
    float* out = (float*)d_out;

    // ws layout (bytes):
    //   cnt : [0, 800000)                      2*N f32
    //   agg : [800000, 800000+51200000)        2*N*64 f32 (layer1 uses first 2*N*32)
    //   h1  : [52000000, 77600000)             N*64 f32
    char* ws = (char*)d_ws;
    float* cnt = (float*)(ws);
    float* agg = (float*)(ws + 800000);
    float* h1  = (float*)(ws + 800000 + 51200000);

    // zero cnt + layer-1 agg (contiguous: 800000 + 2*N*32*4 bytes)
    hipMemsetAsync(cnt, 0, 800000 + 2ull * N_NODES * IN_DIM * 4, stream);

    k_scatter1<<<(N_EDGES * 32) / 256, 256, 0, stream>>>(x, ei, ea, agg, cnt);

    int grid_nodes = (N_NODES + NODES_PER_BLOCK - 1) / NODES_PER_BLOCK;  // 1563
    k_layer1<<<grid_nodes, 256, 0, stream>>>(x, agg, cnt, root1, W1, b1, h1);

    hipMemsetAsync(agg, 0, 2ull * N_NODES * HID_DIM * 4, stream);

    k_scatter2<<<(N_EDGES * 64) / 256, 256, 0, stream>>>(h1, ei, ea, agg);

    k_layer2_cls<<<grid_nodes, 256, 0, stream>>>(h1, agg, cnt, root2, W2, b2, Wc, bc, out);
}